// Round 5
// baseline (418.824 us; speedup 1.0000x reference)
//
#include <hip/hip_runtime.h>
#include <math.h>

#define OBS 114
#define ROWS_PER_BLOCK 16   // 2 waves x 8 rows

__device__ __forceinline__ float fast_tanh(float x) {
    float e = __expf(2.0f * x);
    return 1.0f - 2.0f * __builtin_amdgcn_rcpf(e + 1.0f);
}

template<int CTRL>
__device__ __forceinline__ float dpp_add(float x) {
    int y = __builtin_amdgcn_update_dpp(0, __float_as_int(x), CTRL, 0xF, 0xF, true);
    return x + __int_as_float(y);
}
// sum across each 16-lane row (serves 4 rows per wave simultaneously)
__device__ __forceinline__ float row16_sum(float x) {
    x = dpp_add<0xB1>(x);    // quad_perm xor1
    x = dpp_add<0x4E>(x);    // quad_perm xor2
    x = dpp_add<0x124>(x);   // row_ror:4
    x = dpp_add<0x128>(x);   // row_ror:8
    return x;
}
__device__ __forceinline__ float f4c(const float4& v, int j) {
    return j==0?v.x: j==1?v.y: j==2?v.z: v.w;
}

// ---- repack [K x 100] row-major weights into [K][16 j][8 i] so each lane's
// 7 h-slots (h = j+16i) are 2 contiguous float4 loads ----
__global__ __launch_bounds__(256) void repack_kernel(
    const float* __restrict__ Ac, const float* __restrict__ Lc,
    const float* __restrict__ fcW, const float* __restrict__ f1W,
    const float* __restrict__ f2W, float* __restrict__ ws)
{
    int tid = blockIdx.x*256 + threadIdx.x;   // 800 krows * 128
    if (tid >= 800*128) return;
    int krow = tid >> 7;
    int idx  = tid & 127;
    int j = idx >> 3, i = idx & 7;
    int h = j + 16*i;
    const float* src; int k;
    if (krow < 100)      { src = Ac;  k = krow; }
    else if (krow < 200) { src = Lc;  k = krow-100; }
    else if (krow < 300) { src = fcW; k = krow-200; }
    else if (krow < 700) { src = f1W; k = krow-300; }
    else                 { src = f2W; k = krow-700; }
    float v = (i < 7 && h < 100) ? src[k*100 + h] : 0.f;
    ws[tid] = v;
}

// acc[i][b] = sum_k s_x4[R_b][k] * Wp[k][j][i]
// Depth-1 software pipeline: k4+1's x-fragments and 8 weight float4s are
// loaded while FMA-ing k4 -> L2 latency overlapped with compute.
template<int NK4>
__device__ __forceinline__ void mm16(const float* __restrict__ Wp,
    const float (*s_x4)[400], int R0, int R1, int j, float acc[7][2])
{
    const float* wp = Wp + j*8;
    float4 xa = *(const float4*)&s_x4[R0][0];
    float4 xb = *(const float4*)&s_x4[R1][0];
    float4 wlo[4], whi[4];
#pragma unroll
    for (int jj=0;jj<4;++jj) {
        wlo[jj] = *(const float4*)(wp + jj*128);
        whi[jj] = *(const float4*)(wp + jj*128 + 4);
    }
#pragma unroll
    for (int i=0;i<7;++i) { acc[i][0]=0.f; acc[i][1]=0.f; }
#pragma unroll 1
    for (int k4 = 0; k4 < NK4; ++k4) {
        float4 cxa = xa, cxb = xb;
        float4 cwlo[4], cwhi[4];
#pragma unroll
        for (int jj=0;jj<4;++jj) { cwlo[jj]=wlo[jj]; cwhi[jj]=whi[jj]; }
        if (k4+1 < NK4) {
            xa = *(const float4*)&s_x4[R0][(k4+1)*4];
            xb = *(const float4*)&s_x4[R1][(k4+1)*4];
            const float* wpn = wp + (size_t)(k4+1)*4*128;
#pragma unroll
            for (int jj=0;jj<4;++jj) {
                wlo[jj] = *(const float4*)(wpn + jj*128);
                whi[jj] = *(const float4*)(wpn + jj*128 + 4);
            }
        }
#pragma unroll
        for (int jj=0;jj<4;++jj) {
            float w[7] = {cwlo[jj].x,cwlo[jj].y,cwlo[jj].z,cwlo[jj].w,
                          cwhi[jj].x,cwhi[jj].y,cwhi[jj].z};
            float xka = f4c(cxa,jj), xkb = f4c(cxb,jj);
#pragma unroll
            for (int i=0;i<7;++i) {
                acc[i][0] = fmaf(xka, w[i], acc[i][0]);
                acc[i][1] = fmaf(xkb, w[i], acc[i][1]);
            }
        }
    }
}

// attention stream, 16-lane layout, batch-interleaved (2 independent chains),
// software-pipelined agent-input loads, q passed via registers.
// va_h = g_h*((sum_n w_n*rinv_n*t_nh) - (sum_n w_n*rinv_n*mean_n))/s + be_h
template<int K, int NA>
__device__ __forceinline__ void attn16(
    const float* __restrict__ W, const float* __restrict__ bb,
    const float* __restrict__ gp, const float* __restrict__ bep,
    const float* __restrict__ in, int xoff,
    float (*s_x4)[400], int seg,
    int rowAc, int rowBc, int RA, int RB,
    const float qacc[7][2],
    const int hc[7], const float msk[7])
{
    float w[K][7], bias[7], g[7], be[7];
#pragma unroll
    for (int i=0;i<7;++i) {
#pragma unroll
        for (int k=0;k<K;++k) w[k][i] = W[k*100 + hc[i]];
        bias[i] = bb[hc[i]]; g[i] = gp[hc[i]]; be[i] = bep[hc[i]];
    }
    float qg[2][7], C1[2];
#pragma unroll
    for (int b=0;b<2;++b) {
        float c = 0.f;
#pragma unroll
        for (int i=0;i<7;++i) { qg[b][i] = qacc[i][b]*g[i]*msk[i]; c += qg[b][i]; }
        C1[b] = row16_sum(c);
    }
    const float* xr0 = in + (size_t)rowAc*OBS + xoff;
    const float* xr1 = in + (size_t)rowBc*OBS + xoff;
    float s[2] = {0.f,0.f}, bacc[2] = {0.f,0.f};
    float A[2][7];
#pragma unroll
    for (int b=0;b<2;++b)
#pragma unroll
        for (int i=0;i<7;++i) A[b][i]=0.f;

    float xc[2][K];
#pragma unroll
    for (int k=0;k<K;++k) { xc[0][k] = xr0[k]; xc[1][k] = xr1[k]; }

#pragma unroll 1
    for (int n=0;n<NA;++n) {
        // prefetch next agent's inputs (depth-2 pipeline)
        int np = (n+1 < NA) ? (n+1) : n;
        float xn[2][K];
#pragma unroll
        for (int k=0;k<K;++k) { xn[0][k] = xr0[np*K+k]; xn[1][k] = xr1[np*K+k]; }

        float t[2][7], sa[2], sq[2], sd[2];
#pragma unroll
        for (int b=0;b<2;++b) { sa[b]=0.f; sq[b]=0.f; sd[b]=0.f; }
#pragma unroll
        for (int i=0;i<7;++i) {
#pragma unroll
            for (int b=0;b<2;++b) {
                float a = bias[i];
#pragma unroll
                for (int k=0;k<K;++k) a = fmaf(xc[b][k], w[k][i], a);
                float tt = fast_tanh(a) * msk[i];
                t[b][i] = tt;
                sa[b] += tt;
                sq[b] = fmaf(tt,tt,sq[b]);
                sd[b] = fmaf(qg[b][i],tt,sd[b]);
            }
        }
#pragma unroll
        for (int b=0;b<2;++b) { sa[b]=row16_sum(sa[b]); sq[b]=row16_sum(sq[b]); sd[b]=row16_sum(sd[b]); }
#pragma unroll
        for (int b=0;b<2;++b) {
            float mean = sa[b]*0.01f;
            float var  = fmaf(sq[b],0.01f,-mean*mean);
            float rinv = __builtin_amdgcn_rsqf(var + 1e-5f);
            float logit = (sd[b]-mean*C1[b])*rinv;   // q.be term agent-constant -> dropped
            float wgt = __expf(fminf(logit,80.f));
            s[b] += wgt;
            float wr = wgt*rinv;
            bacc[b] = fmaf(wr,mean,bacc[b]);
#pragma unroll
            for (int i=0;i<7;++i) A[b][i] = fmaf(wr,t[b][i],A[b][i]);
        }
#pragma unroll
        for (int k=0;k<K;++k) { xc[0][k]=xn[0][k]; xc[1][k]=xn[1][k]; }
    }
#pragma unroll
    for (int b=0;b<2;++b) {
        int R = b ? RB : RA;
        float inv = __builtin_amdgcn_rcpf(s[b]);
#pragma unroll
        for (int i=0;i<7;++i)
            if (msk[i]>0.f) s_x4[R][seg+hc[i]] = fmaf(g[i], (A[b][i]-bacc[b])*inv, be[i]);
    }
}

// LN(tanh(acc+bias)) for both batches, batch-interleaved
__device__ __forceinline__ void ln_pair(const float acc[7][2],
    const float* __restrict__ bp, const float* __restrict__ gp, const float* __restrict__ bep,
    const int hc[7], const float msk[7], float outv[2][7])
{
    float bias[7], g[7], be[7];
#pragma unroll
    for (int i=0;i<7;++i) { bias[i]=bp[hc[i]]; g[i]=gp[hc[i]]; be[i]=bep[hc[i]]; }
    float t[2][7], sa[2], sq[2];
#pragma unroll
    for (int b=0;b<2;++b) { sa[b]=0.f; sq[b]=0.f; }
#pragma unroll
    for (int i=0;i<7;++i) {
#pragma unroll
        for (int b=0;b<2;++b) {
            float tt = fast_tanh(acc[i][b] + bias[i]) * msk[i];
            t[b][i] = tt; sa[b] += tt; sq[b] = fmaf(tt,tt,sq[b]);
        }
    }
#pragma unroll
    for (int b=0;b<2;++b) { sa[b]=row16_sum(sa[b]); sq[b]=row16_sum(sq[b]); }
#pragma unroll
    for (int b=0;b<2;++b) {
        float mean = sa[b]*0.01f;
        float var  = fmaf(sq[b],0.01f,-mean*mean);
        float rinv = __builtin_amdgcn_rsqf(var + 1e-5f);
#pragma unroll
        for (int i=0;i<7;++i) outv[b][i] = fmaf((t[b][i]-mean)*rinv, g[i], be[i]);
    }
}

__global__ __launch_bounds__(128, 3)
void obs_encoder_kernel(const float* __restrict__ in,
    const float* __restrict__ sW, const float* __restrict__ sb, const float* __restrict__ sg, const float* __restrict__ sbe,
    const float* __restrict__ oW, const float* __restrict__ ob, const float* __restrict__ og, const float* __restrict__ obe,
    const float* __restrict__ lW, const float* __restrict__ lb, const float* __restrict__ lg, const float* __restrict__ lbe,
    const float* __restrict__ gW, const float* __restrict__ gb, const float* __restrict__ gg_, const float* __restrict__ gbe,
    const float* __restrict__ fcb, const float* __restrict__ fcg, const float* __restrict__ fcbe,
    const float* __restrict__ f1b, const float* __restrict__ f1g, const float* __restrict__ f1be,
    const float* __restrict__ f2b, const float* __restrict__ f2g, const float* __restrict__ f2be,
    const float* __restrict__ wsf,
    float* __restrict__ out, int B)
{
    const int lane = threadIdx.x & 63;
    const int wv   = threadIdx.x >> 6;
    const int j    = lane & 15;
    const int rw   = lane >> 4;
    const int rowBase = blockIdx.x*ROWS_PER_BLOCK + wv*8;
    const int rowA = rowBase + rw;        // batch 0
    const int rowB = rowBase + 4 + rw;    // batch 1
    const int RA = wv*8 + rw, RB = RA + 4;
    const int rowAc = min(rowA, B-1), rowBc = min(rowB, B-1);

    int hc[7]; float msk[7];
#pragma unroll
    for (int i=0;i<7;++i) {
        int h = j + 16*i;
        bool v = h < 100;
        hc[i] = v ? h : 99;
        msk[i] = v ? 1.f : 0.f;
    }

    // segments: [0:100) emb -> gi -> h1 (serial reuse), [100:200) va,
    // [200:300) vl, [300:400) vg.  Waves touch disjoint R -> no barriers.
    __shared__ __align__(16) float s_x4[ROWS_PER_BLOCK][400];

    const float* Acp = wsf;
    const float* Lcp = wsf + 12800;
    const float* fcp = wsf + 25600;
    const float* f1p = wsf + 38400;
    const float* f2p = wsf + 89600;

    // ---- self encoder -> s_x4[:, 0:100] ----
    {
        float w[4][7], bias[7], g[7], be[7];
#pragma unroll
        for (int i=0;i<7;++i) {
#pragma unroll
            for (int k=0;k<4;++k) w[k][i] = sW[k*100 + hc[i]];
            bias[i] = sb[hc[i]]; g[i] = sg[hc[i]]; be[i] = sbe[hc[i]];
        }
        const float* xr0 = in + (size_t)rowAc*OBS;
        const float* xr1 = in + (size_t)rowBc*OBS;
        float x[2][4];
#pragma unroll
        for (int k=0;k<4;++k) { x[0][k]=xr0[k]; x[1][k]=xr1[k]; }
        float t[2][7], sa[2], sq[2];
#pragma unroll
        for (int b=0;b<2;++b) { sa[b]=0.f; sq[b]=0.f; }
#pragma unroll
        for (int i=0;i<7;++i) {
#pragma unroll
            for (int b=0;b<2;++b) {
                float a = bias[i];
#pragma unroll
                for (int k=0;k<4;++k) a = fmaf(x[b][k], w[k][i], a);
                float tt = fast_tanh(a) * msk[i];
                t[b][i] = tt; sa[b] += tt; sq[b] = fmaf(tt,tt,sq[b]);
            }
        }
#pragma unroll
        for (int b=0;b<2;++b) { sa[b]=row16_sum(sa[b]); sq[b]=row16_sum(sq[b]); }
#pragma unroll
        for (int b=0;b<2;++b) {
            int R = b ? RB : RA;
            float mean = sa[b]*0.01f;
            float var  = fmaf(sq[b],0.01f,-mean*mean);
            float rinv = __builtin_amdgcn_rsqf(var + 1e-5f);
#pragma unroll
            for (int i=0;i<7;++i)
                if (msk[i] > 0.f) s_x4[R][hc[i]] = fmaf((t[b][i]-mean)*rinv, g[i], be[i]);
        }
    }

    // ---- qa = emb@Ac, ql = emb@Lc (kept in registers) ----
    float accA[7][2], accL[7][2];
    mm16<25>(Acp, s_x4, RA, RB, j, accA);
    mm16<25>(Lcp, s_x4, RA, RB, j, accL);

    // ---- gi = LN(tanh(emb@fcW + fcb)) -> seg 0 (overwrites emb) ----
    {
        float accF[7][2];
        mm16<25>(fcp, s_x4, RA, RB, j, accF);
        float outv[2][7];
        ln_pair(accF, fcb, fcg, fcbe, hc, msk, outv);
#pragma unroll
        for (int b=0;b<2;++b) {
            int R = b ? RB : RA;
#pragma unroll
            for (int i=0;i<7;++i)
                if (msk[i] > 0.f) s_x4[R][hc[i]] = outv[b][i];
        }
    }

    // ---- attention streams (ql reused for goal per ref bug) ----
    attn16<2,15>(oW, ob, og,  obe, in, 52, s_x4, 100, rowAc, rowBc, RA, RB, accA, hc, msk);
    attn16<3,16>(lW, lb, lg,  lbe, in, 4,  s_x4, 200, rowAc, rowBc, RA, RB, accL, hc, msk);
    attn16<2,16>(gW, gb, gg_, gbe, in, 82, s_x4, 300, rowAc, rowBc, RA, RB, accL, hc, msk);

    // ---- f1: [400] -> [100], LN -> seg 0 ----
    {
        float acc[7][2];
        mm16<100>(f1p, s_x4, RA, RB, j, acc);
        float outv[2][7];
        ln_pair(acc, f1b, f1g, f1be, hc, msk, outv);
#pragma unroll
        for (int b=0;b<2;++b) {
            int R = b ? RB : RA;
#pragma unroll
            for (int i=0;i<7;++i)
                if (msk[i] > 0.f) s_x4[R][hc[i]] = outv[b][i];
        }
    }

    // ---- f2: [100] -> [100], LN -> out ----
    {
        float acc[7][2];
        mm16<25>(f2p, s_x4, RA, RB, j, acc);
        float outv[2][7];
        ln_pair(acc, f2b, f2g, f2be, hc, msk, outv);
#pragma unroll
        for (int b=0;b<2;++b) {
            int row = b ? rowB : rowA;
            if (row < B) {
#pragma unroll
                for (int i=0;i<7;++i)
                    if (msk[i] > 0.f)
                        out[(size_t)row*100 + hc[i]] = outv[b][i];
            }
        }
    }
}

extern "C" void kernel_launch(void* const* d_in, const int* in_sizes, int n_in,
                              void* d_out, int out_size, void* d_ws, size_t ws_size,
                              hipStream_t stream) {
    const float* in  = (const float*)d_in[0];
    const float* sW  = (const float*)d_in[2];
    const float* sb  = (const float*)d_in[3];
    const float* sg  = (const float*)d_in[4];
    const float* sbe = (const float*)d_in[5];
    const float* oW  = (const float*)d_in[6];
    const float* ob  = (const float*)d_in[7];
    const float* og  = (const float*)d_in[8];
    const float* obe = (const float*)d_in[9];
    const float* lW  = (const float*)d_in[10];
    const float* lb  = (const float*)d_in[11];
    const float* lg  = (const float*)d_in[12];
    const float* lbe = (const float*)d_in[13];
    const float* gW  = (const float*)d_in[14];
    const float* gb  = (const float*)d_in[15];
    const float* gg  = (const float*)d_in[16];
    const float* gbe = (const float*)d_in[17];
    const float* Ac  = (const float*)d_in[18];
    const float* Lc  = (const float*)d_in[19];
    const float* fcW = (const float*)d_in[20];
    const float* fcb = (const float*)d_in[21];
    const float* fcg = (const float*)d_in[22];
    const float* fcbe= (const float*)d_in[23];
    const float* f1W = (const float*)d_in[24];
    const float* f1b = (const float*)d_in[25];
    const float* f1g = (const float*)d_in[26];
    const float* f1be= (const float*)d_in[27];
    const float* f2W = (const float*)d_in[28];
    const float* f2b = (const float*)d_in[29];
    const float* f2g = (const float*)d_in[30];
    const float* f2be= (const float*)d_in[31];
    float* out = (float*)d_out;
    float* wsf = (float*)d_ws;

    int B = in_sizes[0] / OBS;
    repack_kernel<<<(800*128 + 255)/256, 256, 0, stream>>>(Ac, Lc, fcW, f1W, f2W, wsf);
    int blocks = (B + ROWS_PER_BLOCK - 1) / ROWS_PER_BLOCK;
    obs_encoder_kernel<<<blocks, 128, 0, stream>>>(in,
        sW, sb, sg, sbe, oW, ob, og, obe, lW, lb, lg, lbe, gW, gb, gg, gbe,
        fcb, fcg, fcbe, f1b, f1g, f1be, f2b, f2g, f2be,
        wsf, out, B);
}

// Round 7
// 369.367 us; speedup vs baseline: 1.1339x; 1.1339x over previous
//
#include <hip/hip_runtime.h>
#include <math.h>

#define OBS 114
#define ROWS_PER_BLOCK 16   // 2 waves x 8 rows
#define BSTRIDE 104         // fp32 buffer row stride (100 + pad)

__device__ __forceinline__ float fast_tanh(float x) {
    float e = __expf(2.0f * x);
    return 1.0f - 2.0f * __builtin_amdgcn_rcpf(e + 1.0f);
}

template<int CTRL>
__device__ __forceinline__ float dpp_add(float x) {
    int y = __builtin_amdgcn_update_dpp(0, __float_as_int(x), CTRL, 0xF, 0xF, true);
    return x + __int_as_float(y);
}
// sum across each 16-lane row (serves 4 rows per wave simultaneously)
__device__ __forceinline__ float row16_sum(float x) {
    x = dpp_add<0xB1>(x);    // quad_perm xor1
    x = dpp_add<0x4E>(x);    // quad_perm xor2
    x = dpp_add<0x124>(x);   // row_ror:4
    x = dpp_add<0x128>(x);   // row_ror:8
    return x;
}
__device__ __forceinline__ float f4c(const float4& v, int j) {
    return j==0?v.x: j==1?v.y: j==2?v.z: v.w;
}

// ---- repack [K x 100] row-major weights into [K][16 j][8 i] so each lane's
// 7 h-slots (h = j+16i) are 2 contiguous float4 loads; masked slots -> 0 ----
__global__ __launch_bounds__(256) void repack_kernel(
    const float* __restrict__ Ac, const float* __restrict__ Lc,
    const float* __restrict__ fcW, const float* __restrict__ f1W,
    const float* __restrict__ f2W, float* __restrict__ ws)
{
    int tid = blockIdx.x*256 + threadIdx.x;   // 800 krows * 128
    if (tid >= 800*128) return;
    int krow = tid >> 7;
    int idx  = tid & 127;
    int j = idx >> 3, i = idx & 7;
    int h = j + 16*i;
    const float* src; int k;
    if (krow < 100)      { src = Ac;  k = krow; }
    else if (krow < 200) { src = Lc;  k = krow-100; }
    else if (krow < 300) { src = fcW; k = krow-200; }
    else if (krow < 700) { src = f1W; k = krow-300; }
    else                 { src = f2W; k = krow-700; }
    float v = (i < 7 && h < 100) ? src[k*100 + h] : 0.f;
    ws[tid] = v;
}

// acc[i][b] += sum_k sbuf[R_b][k] * Wp[k][j][i]  (accumulating; zero acc outside)
template<int NK4>
__device__ __forceinline__ void mm16(const float* __restrict__ Wp,
    const float (*sbuf)[BSTRIDE], int R0, int R1, int j, float acc[7][2])
{
    const float* wp = Wp + j*8;
#pragma unroll 2
    for (int k4 = 0; k4 < NK4; ++k4) {
        float4 xa = *(const float4*)&sbuf[R0][k4*4];
        float4 xb = *(const float4*)&sbuf[R1][k4*4];
#pragma unroll
        for (int jj=0;jj<4;++jj) {
            const float* w8 = wp + (size_t)(k4*4+jj)*128;
            float4 wlo = *(const float4*)w8;
            float4 whi = *(const float4*)(w8+4);
            float w[7] = {wlo.x,wlo.y,wlo.z,wlo.w,whi.x,whi.y,whi.z};
            float xka = f4c(xa,jj), xkb = f4c(xb,jj);
#pragma unroll
            for (int i=0;i<7;++i) {
                acc[i][0] = fmaf(xka, w[i], acc[i][0]);
                acc[i][1] = fmaf(xkb, w[i], acc[i][1]);
            }
        }
    }
}

// attention stream, 16-lane layout, batch-interleaved (2 independent chains).
// Pre-masked params: masked slots have w=bias=g=0 -> t=tanh(0)=0 contributes nothing.
// Writes result segment into sbuf[R][h].
template<int K, int NA>
__device__ __forceinline__ void attn16(
    const float* __restrict__ W, const float* __restrict__ bb,
    const float* __restrict__ gp, const float* __restrict__ bep,
    const float* __restrict__ in, int xoff,
    float (*sbuf)[BSTRIDE],
    int rowAc, int rowBc, int RA, int RB,
    const float qacc[7][2],
    const int hc[7], const float msk[7])
{
    float w[K][7], bias[7], g[7], be[7];
#pragma unroll
    for (int i=0;i<7;++i) {
#pragma unroll
        for (int k=0;k<K;++k) w[k][i] = W[k*100 + hc[i]] * msk[i];
        bias[i] = bb[hc[i]] * msk[i];
        g[i]    = gp[hc[i]] * msk[i];
        be[i]   = bep[hc[i]];
    }
    float qg[2][7], C1[2];
#pragma unroll
    for (int b=0;b<2;++b) {
        float c = 0.f;
#pragma unroll
        for (int i=0;i<7;++i) { qg[b][i] = qacc[i][b]*g[i]; c += qg[b][i]; }
        C1[b] = row16_sum(c);
    }
    const float* xr0 = in + (size_t)rowAc*OBS + xoff;
    const float* xr1 = in + (size_t)rowBc*OBS + xoff;
    float s[2] = {0.f,0.f}, bacc[2] = {0.f,0.f};
    float A[2][7];
#pragma unroll
    for (int b=0;b<2;++b)
#pragma unroll
        for (int i=0;i<7;++i) A[b][i]=0.f;

#pragma unroll 1
    for (int n=0;n<NA;++n) {
        float x0[K], x1[K];
#pragma unroll
        for (int k=0;k<K;++k) { x0[k] = xr0[n*K+k]; x1[k] = xr1[n*K+k]; }
        float t[2][7], sa[2], sq[2], sd[2];
#pragma unroll
        for (int b=0;b<2;++b) { sa[b]=0.f; sq[b]=0.f; sd[b]=0.f; }
#pragma unroll
        for (int i=0;i<7;++i) {
#pragma unroll
            for (int b=0;b<2;++b) {
                float a = bias[i];
#pragma unroll
                for (int k=0;k<K;++k) a = fmaf(b ? x1[k] : x0[k], w[k][i], a);
                float tt = fast_tanh(a);
                t[b][i] = tt;
                sa[b] += tt;
                sq[b] = fmaf(tt,tt,sq[b]);
                sd[b] = fmaf(qg[b][i],tt,sd[b]);
            }
        }
#pragma unroll
        for (int b=0;b<2;++b) { sa[b]=row16_sum(sa[b]); sq[b]=row16_sum(sq[b]); sd[b]=row16_sum(sd[b]); }
#pragma unroll
        for (int b=0;b<2;++b) {
            float mean = sa[b]*0.01f;
            float var  = fmaf(sq[b],0.01f,-mean*mean);
            float rinv = __builtin_amdgcn_rsqf(var + 1e-5f);
            float logit = (sd[b]-mean*C1[b])*rinv;   // q.be term agent-constant -> dropped
            float wgt = __expf(fminf(logit,80.f));
            s[b] += wgt;
            float wr = wgt*rinv;
            bacc[b] = fmaf(wr,mean,bacc[b]);
#pragma unroll
            for (int i=0;i<7;++i) A[b][i] = fmaf(wr,t[b][i],A[b][i]);
        }
    }
#pragma unroll
    for (int b=0;b<2;++b) {
        int R = b ? RB : RA;
        float inv = __builtin_amdgcn_rcpf(s[b]);
#pragma unroll
        for (int i=0;i<7;++i)
            if (msk[i]>0.f) sbuf[R][hc[i]] = fmaf(g[i], (A[b][i]-bacc[b])*inv, be[i]);
    }
}

// LN(tanh(acc+bias)) for both batches; masked slots: acc=0 (zeroed weights), bias=0.
__device__ __forceinline__ void ln_pair(const float acc[7][2],
    const float* __restrict__ bp, const float* __restrict__ gp, const float* __restrict__ bep,
    const int hc[7], const float msk[7], float outv[2][7])
{
    float bias[7], g[7], be[7];
#pragma unroll
    for (int i=0;i<7;++i) { bias[i]=bp[hc[i]]*msk[i]; g[i]=gp[hc[i]]; be[i]=bep[hc[i]]; }
    float t[2][7], sa[2], sq[2];
#pragma unroll
    for (int b=0;b<2;++b) { sa[b]=0.f; sq[b]=0.f; }
#pragma unroll
    for (int i=0;i<7;++i) {
#pragma unroll
        for (int b=0;b<2;++b) {
            float tt = fast_tanh(acc[i][b] + bias[i]);
            t[b][i] = tt; sa[b] += tt*msk[i]; sq[b] = fmaf(tt*msk[i],tt,sq[b]);
        }
    }
#pragma unroll
    for (int b=0;b<2;++b) { sa[b]=row16_sum(sa[b]); sq[b]=row16_sum(sq[b]); }
#pragma unroll
    for (int b=0;b<2;++b) {
        float mean = sa[b]*0.01f;
        float var  = fmaf(sq[b],0.01f,-mean*mean);
        float rinv = __builtin_amdgcn_rsqf(var + 1e-5f);
#pragma unroll
        for (int i=0;i<7;++i) outv[b][i] = fmaf((t[b][i]-mean)*rinv, g[i], be[i]);
    }
}

__global__ __launch_bounds__(128, 4)
void obs_encoder_kernel(const float* __restrict__ in,
    const float* __restrict__ sW, const float* __restrict__ sb, const float* __restrict__ sg, const float* __restrict__ sbe,
    const float* __restrict__ oW, const float* __restrict__ ob, const float* __restrict__ og, const float* __restrict__ obe,
    const float* __restrict__ lW, const float* __restrict__ lb, const float* __restrict__ lg, const float* __restrict__ lbe,
    const float* __restrict__ gW, const float* __restrict__ gb, const float* __restrict__ gg_, const float* __restrict__ gbe,
    const float* __restrict__ fcb, const float* __restrict__ fcg, const float* __restrict__ fcbe,
    const float* __restrict__ f1b, const float* __restrict__ f1g, const float* __restrict__ f1be,
    const float* __restrict__ f2b, const float* __restrict__ f2g, const float* __restrict__ f2be,
    const float* __restrict__ wsf,
    float* __restrict__ out, int B)
{
    const int lane = threadIdx.x & 63;
    const int wv   = threadIdx.x >> 6;
    const int j    = lane & 15;
    const int rw   = lane >> 4;
    const int rowBase = blockIdx.x*ROWS_PER_BLOCK + wv*8;
    const int rowA = rowBase + rw;        // batch 0
    const int rowB = rowBase + 4 + rw;    // batch 1
    const int RA = wv*8 + rw, RB = RA + 4;
    const int rowAc = min(rowA, B-1), rowBc = min(rowB, B-1);

    int hc[7]; float msk[7];
#pragma unroll
    for (int i=0;i<7;++i) {
        int h = j + 16*i;
        bool v = h < 100;
        hc[i] = v ? h : 99;
        msk[i] = v ? 1.f : 0.f;
    }

    // Single reusable fp32 segment buffer: emb -> gi -> va -> vl -> vg -> h1.
    // f1 is accumulated incrementally (f1W split into 4 k-blocks), so the
    // [16][400] concat never materializes: LDS = 16*104*4 = 6.6 KB -> full
    // grid resident in one round.  Waves touch disjoint rows -> no barriers.
    __shared__ __align__(16) float sbuf[ROWS_PER_BLOCK][BSTRIDE];

    const float* Acp = wsf;
    const float* Lcp = wsf + 12800;
    const float* fcp = wsf + 25600;
    const float* f1p = wsf + 38400;
    const float* f2p = wsf + 89600;

    // ---- self encoder -> sbuf ----
    {
        float w[4][7], bias[7], g[7], be[7];
#pragma unroll
        for (int i=0;i<7;++i) {
#pragma unroll
            for (int k=0;k<4;++k) w[k][i] = sW[k*100 + hc[i]] * msk[i];
            bias[i] = sb[hc[i]] * msk[i]; g[i] = sg[hc[i]]; be[i] = sbe[hc[i]];
        }
        const float* xr0 = in + (size_t)rowAc*OBS;
        const float* xr1 = in + (size_t)rowBc*OBS;
        float x[2][4];
#pragma unroll
        for (int k=0;k<4;++k) { x[0][k]=xr0[k]; x[1][k]=xr1[k]; }
        float t[2][7], sa[2], sq[2];
#pragma unroll
        for (int b=0;b<2;++b) { sa[b]=0.f; sq[b]=0.f; }
#pragma unroll
        for (int i=0;i<7;++i) {
#pragma unroll
            for (int b=0;b<2;++b) {
                float a = bias[i];
#pragma unroll
                for (int k=0;k<4;++k) a = fmaf(x[b][k], w[k][i], a);
                float tt = fast_tanh(a);
                t[b][i] = tt; sa[b] += tt*msk[i]; sq[b] = fmaf(tt*msk[i],tt,sq[b]);
            }
        }
#pragma unroll
        for (int b=0;b<2;++b) { sa[b]=row16_sum(sa[b]); sq[b]=row16_sum(sq[b]); }
#pragma unroll
        for (int b=0;b<2;++b) {
            int R = b ? RB : RA;
            float mean = sa[b]*0.01f;
            float var  = fmaf(sq[b],0.01f,-mean*mean);
            float rinv = __builtin_amdgcn_rsqf(var + 1e-5f);
#pragma unroll
            for (int i=0;i<7;++i)
                if (msk[i] > 0.f) sbuf[R][hc[i]] = fmaf((t[b][i]-mean)*rinv, g[i], be[i]);
        }
    }

    // ---- qa = emb@Ac, ql = emb@Lc, tg = emb@fcW (emb still in sbuf) ----
    float accA[7][2], accL[7][2], accF[7][2];
#pragma unroll
    for (int i=0;i<7;++i) { accA[i][0]=accA[i][1]=accL[i][0]=accL[i][1]=accF[i][0]=accF[i][1]=0.f; }
    mm16<25>(Acp, sbuf, RA, RB, j, accA);
    mm16<25>(Lcp, sbuf, RA, RB, j, accL);
    mm16<25>(fcp, sbuf, RA, RB, j, accF);

    float f1a[7][2];
#pragma unroll
    for (int i=0;i<7;++i) { f1a[i][0]=0.f; f1a[i][1]=0.f; }

    // ---- gi = LN(tanh(tg + fcb)) -> sbuf (overwrites emb), f1 partial k 0..99 ----
    {
        float outv[2][7];
        ln_pair(accF, fcb, fcg, fcbe, hc, msk, outv);
#pragma unroll
        for (int b=0;b<2;++b) {
            int R = b ? RB : RA;
#pragma unroll
            for (int i=0;i<7;++i)
                if (msk[i] > 0.f) sbuf[R][hc[i]] = outv[b][i];
        }
    }
    mm16<25>(f1p, sbuf, RA, RB, j, f1a);

    // ---- attention streams interleaved with f1 partials (ql reused for goal per ref bug) ----
    attn16<2,15>(oW, ob, og,  obe, in, 52, sbuf, rowAc, rowBc, RA, RB, accA, hc, msk);
    mm16<25>(f1p + 100*128, sbuf, RA, RB, j, f1a);
    attn16<3,16>(lW, lb, lg,  lbe, in, 4,  sbuf, rowAc, rowBc, RA, RB, accL, hc, msk);
    mm16<25>(f1p + 200*128, sbuf, RA, RB, j, f1a);
    attn16<2,16>(gW, gb, gg_, gbe, in, 82, sbuf, rowAc, rowBc, RA, RB, accL, hc, msk);
    mm16<25>(f1p + 300*128, sbuf, RA, RB, j, f1a);

    // ---- h1 = LN(tanh(f1a + f1b)) -> sbuf ----
    {
        float outv[2][7];
        ln_pair(f1a, f1b, f1g, f1be, hc, msk, outv);
#pragma unroll
        for (int b=0;b<2;++b) {
            int R = b ? RB : RA;
#pragma unroll
            for (int i=0;i<7;++i)
                if (msk[i] > 0.f) sbuf[R][hc[i]] = outv[b][i];
        }
    }

    // ---- f2: [100] -> [100], LN -> out ----
    {
        float acc[7][2];
#pragma unroll
        for (int i=0;i<7;++i) { acc[i][0]=0.f; acc[i][1]=0.f; }
        mm16<25>(f2p, sbuf, RA, RB, j, acc);
        float outv[2][7];
        ln_pair(acc, f2b, f2g, f2be, hc, msk, outv);
#pragma unroll
        for (int b=0;b<2;++b) {
            int row = b ? rowB : rowA;
            if (row < B) {
#pragma unroll
                for (int i=0;i<7;++i)
                    if (msk[i] > 0.f)
                        out[(size_t)row*100 + hc[i]] = outv[b][i];
            }
        }
    }
}

extern "C" void kernel_launch(void* const* d_in, const int* in_sizes, int n_in,
                              void* d_out, int out_size, void* d_ws, size_t ws_size,
                              hipStream_t stream) {
    const float* in  = (const float*)d_in[0];
    const float* sW  = (const float*)d_in[2];
    const float* sb  = (const float*)d_in[3];
    const float* sg  = (const float*)d_in[4];
    const float* sbe = (const float*)d_in[5];
    const float* oW  = (const float*)d_in[6];
    const float* ob  = (const float*)d_in[7];
    const float* og  = (const float*)d_in[8];
    const float* obe = (const float*)d_in[9];
    const float* lW  = (const float*)d_in[10];
    const float* lb  = (const float*)d_in[11];
    const float* lg  = (const float*)d_in[12];
    const float* lbe = (const float*)d_in[13];
    const float* gW  = (const float*)d_in[14];
    const float* gb  = (const float*)d_in[15];
    const float* gg  = (const float*)d_in[16];
    const float* gbe = (const float*)d_in[17];
    const float* Ac  = (const float*)d_in[18];
    const float* Lc  = (const float*)d_in[19];
    const float* fcW = (const float*)d_in[20];
    const float* fcb = (const float*)d_in[21];
    const float* fcg = (const float*)d_in[22];
    const float* fcbe= (const float*)d_in[23];
    const float* f1W = (const float*)d_in[24];
    const float* f1b = (const float*)d_in[25];
    const float* f1g = (const float*)d_in[26];
    const float* f1be= (const float*)d_in[27];
    const float* f2W = (const float*)d_in[28];
    const float* f2b = (const float*)d_in[29];
    const float* f2g = (const float*)d_in[30];
    const float* f2be= (const float*)d_in[31];
    float* out = (float*)d_out;
    float* wsf = (float*)d_ws;

    int B = in_sizes[0] / OBS;
    repack_kernel<<<(800*128 + 255)/256, 256, 0, stream>>>(Ac, Lc, fcW, f1W, f2W, wsf);
    int blocks = (B + ROWS_PER_BLOCK - 1) / ROWS_PER_BLOCK;
    obs_encoder_kernel<<<blocks, 128, 0, stream>>>(in,
        sW, sb, sg, sbe, oW, ob, og, obe, lW, lb, lg, lbe, gW, gb, gg, gbe,
        fcb, fcg, fcbe, f1b, f1g, f1be, f2b, f2g, f2be,
        wsf, out, B);
}